// Round 2
// 96.502 us; speedup vs baseline: 1.0039x; 1.0039x over previous
//
#include <hip/hip_runtime.h>
#include <hip/hip_bf16.h>

// Problem constants (B, N, K, P, D, F, H) = (8, 20, 2, 320, 3, 64, 64)
// Inputs: float32 (nbr_idx int32). Output: float32.
constexpr int B_ = 8, N_ = 20, K_ = 2, P_ = 320, D_ = 3, F_ = 64, H_ = 64;
constexpr int Q_ = K_ * P_;          // 640 = flattened (K,P) of a node
constexpr float EPS_ = 1e-8f;
constexpr float LOG2E_ = 1.4426950408889634f;

// Packed fp32 (VOP3P) helpers. gfx950's 157.3 TF fp32 rate is only reachable
// via v_pk_* — the scalar q-loop was main-VALU-issue-bound.
// NOTE: gfx950 has NO v_pk_max_f32 (only pk_fma/pk_mul/pk_add fp32) — ReLU is
// done as two scalar v_max_f32 on the packed halves.
typedef float v2f __attribute__((ext_vector_type(2)));

__device__ __forceinline__ v2f mk2(float a, float b) { v2f r; r.x = a; r.y = b; return r; }

__device__ __forceinline__ v2f pk_fma(v2f a, v2f b, v2f c) {
    v2f d;
    asm("v_pk_fma_f32 %0, %1, %2, %3" : "=v"(d) : "v"(a), "v"(b), "v"(c));
    return d;
}

// One block per (b, n). 640 threads: thread = one output row (k,p), k = tid/320.
// 320 = 5 full waves -> k is wave-uniform -> LDS q-loop reads are broadcasts.
//
// SoA-pair LDS layout: pair index t covers q = 2t, 2t+1:
//   xnA[k][t] = (x_e, x_o, y_e, y_o)
//   xnB[k][t] = (z_e, z_o, c_e, c_o),  c_q = Wnb_q/sumW * exp2(-2*log2e*|xn_q|^2)
// Per 2 q's: 2 uniform ds_read_b128 + 3 v_pk_fma (dot, with -2L|a|^2 folded into
// the fma tail) + 2 v_exp_f32 + 1 v_pk_fma (acc)  -> main-pipe instrs halved vs
// the scalar version. The (f4.x,f4.y)/(f4.z,f4.w) sub-pairs of a b128 dest are
// even-aligned VGPR pairs, so the packed operands need no v_movs.
__global__ __launch_bounds__(Q_) void dnbp_kernel(
    const float* __restrict__ X,      // (B,N,K,P,D)
    const float* __restrict__ W,      // (B,N,K,P)
    const float* __restrict__ feats,  // (B,N,F)
    const float* __restrict__ mu,     // (N,K,D)
    const float* __restrict__ W1,     // (N,F,H)
    const float* __restrict__ Wx,     // (N,D,H)
    const float* __restrict__ b1,     // (N,H)
    const float* __restrict__ W2,     // (N,H)
    const float* __restrict__ bias2,  // (N,)
    const int* __restrict__ nbr,      // (N,2)
    float* __restrict__ out)          // (B,N,K,P) float32
{
    __shared__ float4 xnA[K_][Q_ / 2];   // (x,x',y,y') pairs
    __shared__ float4 xnB[K_][Q_ / 2];   // (z,z',c,c') pairs
    __shared__ float4 gA[H_ / 2];        // (wx0,wx0',wx1,wx1') pairs
    __shared__ float4 gB[H_ / 2];        // (wx2,wx2',w2,w2') pairs
    __shared__ v2f    hb2[H_ / 2];       // (hf+b1) pairs
    __shared__ float  red[2 * 10];
    __shared__ float  sumW[2];           // 1 / (sum W_neighbor + EPS)
    __shared__ float  totalS;            // 1 / (sum w + EPS)

    const int bn  = blockIdx.x;     // 0..159
    const int b   = bn / N_;
    const int n   = bn - b * N_;
    const int tid = threadIdx.x;    // 0..639
    const int wave = tid >> 6;
    const int lane = tid & 63;

    const int j0 = nbr[n * 2 + 0];
    const int j1 = nbr[n * 2 + 1];

    // ---- gate parameters: hf = feats[b,n] @ W1[n]; pack pair-SoA (threads 0..63) ----
    if (tid < H_) {
        const int h = tid;
        const float* fp  = feats + ((size_t)b * N_ + n) * F_;
        const float* w1p = W1 + (size_t)n * F_ * H_ + h;
        float acc = 0.f;
        #pragma unroll 8
        for (int f = 0; f < F_; ++f)
            acc = fmaf(fp[f], w1p[(size_t)f * H_], acc);
        const int hi = h >> 1, ho = h & 1;
        ((float*)&hb2[hi])[ho] = acc + b1[n * H_ + h];
        const float* wxp = Wx + (size_t)n * D_ * H_ + h;
        float* ga = (float*)&gA[hi];
        float* gb = (float*)&gB[hi];
        ga[ho]     = wxp[0];
        ga[2 + ho] = wxp[H_];
        gb[ho]     = wxp[2 * H_];
        gb[2 + ho] = W2[n * H_ + h];
    }

    // ---- stage both neighbors' X into pair-SoA; c written after sumW known ----
    const int q  = tid;
    const int qi = q >> 1, qo = q & 1;
    float w0, w1, ew0, ew1;
    {
        const size_t base0 = ((size_t)b * N_ + j0) * Q_ + q;
        const float* xp = X + base0 * D_;
        const float x0 = xp[0], x1 = xp[1], x2 = xp[2];
        const float sq = x0 * x0 + x1 * x1 + x2 * x2;
        w0  = W[base0];
        ew0 = __builtin_amdgcn_exp2f(-2.f * LOG2E_ * sq);
        float* a  = (float*)&xnA[0][qi];
        float* bq = (float*)&xnB[0][qi];
        a[qo] = x0; a[2 + qo] = x1; bq[qo] = x2;
    }
    {
        const size_t base1 = ((size_t)b * N_ + j1) * Q_ + q;
        const float* xp = X + base1 * D_;
        const float x0 = xp[0], x1 = xp[1], x2 = xp[2];
        const float sq = x0 * x0 + x1 * x1 + x2 * x2;
        w1  = W[base1];
        ew1 = __builtin_amdgcn_exp2f(-2.f * LOG2E_ * sq);
        float* a  = (float*)&xnA[1][qi];
        float* bq = (float*)&xnB[1][qi];
        a[qo] = x0; a[2 + qo] = x1; bq[qo] = x2;
    }

    // ---- block-reduce neighbor weight sums (both neighbors at once) ----
    {
        float v0 = w0, v1 = w1;
        #pragma unroll
        for (int off = 32; off > 0; off >>= 1) {
            v0 += __shfl_down(v0, off, 64);
            v1 += __shfl_down(v1, off, 64);
        }
        if (lane == 0) { red[wave * 2] = v0; red[wave * 2 + 1] = v1; }
        __syncthreads();
        if (tid == 0) {
            float s0 = 0.f, s1 = 0.f;
            #pragma unroll
            for (int wv = 0; wv < 10; ++wv) { s0 += red[wv * 2]; s1 += red[wv * 2 + 1]; }
            sumW[0] = 1.f / (s0 + EPS_);
            sumW[1] = 1.f / (s1 + EPS_);
        }
        __syncthreads();
    }

    // ---- write c = w * exp2(-2L|xn|^2) * (1/sumW) into the pair slots ----
    ((float*)&xnB[0][qi])[2 + qo] = w0 * ew0 * sumW[0];
    ((float*)&xnB[1][qi])[2 + qo] = w1 * ew1 * sumW[1];
    __syncthreads();

    // ---- per-row work ----
    const int k = (tid >= P_) ? 1 : 0;   // wave-uniform (320 = 5 waves)
    const int p = tid - k * P_;
    const size_t rowbase = (((size_t)b * N_ + n) * K_ + k) * P_ + p;
    const float* xp = X + rowbase * D_;
    const float x0 = xp[0], x1 = xp[1], x2 = xp[2];
    const float* mup = mu + (n * K_ + k) * D_;
    const float a0 = x0 - mup[0];
    const float a1 = x1 - mup[1];
    const float a2 = x2 - mup[2];
    const float ra2 = a0 * a0 + a1 * a1 + a2 * a2;
    // prescale so the packed inner dot directly yields the exp2 argument;
    // -2L*|a|^2 rides in the innermost fma tail (no per-row exp needed).
    const v2f S0 = mk2(a0 * (4.f * LOG2E_), a0 * (4.f * LOG2E_));
    const v2f S1 = mk2(a1 * (4.f * LOG2E_), a1 * (4.f * LOG2E_));
    const v2f S2 = mk2(a2 * (4.f * LOG2E_), a2 * (4.f * LOG2E_));
    const v2f RA = mk2(-2.f * LOG2E_ * ra2, -2.f * LOG2E_ * ra2);

    // gate: u = sigmoid( sum_h relu(hf+b1 + X.Wx)[h] * W2[h] + bias2 ), h-pairs packed
    const v2f X0v = mk2(x0, x0), X1v = mk2(x1, x1), X2v = mk2(x2, x2);
    v2f acc2 = mk2(0.f, 0.f);
    #pragma unroll 4
    for (int i = 0; i < H_ / 2; ++i) {
        const float4 ga = gA[i];
        const float4 gb = gB[i];
        const v2f   hb = hb2[i];
        v2f t = pk_fma(X0v, mk2(ga.x, ga.y),
                pk_fma(X1v, mk2(ga.z, ga.w),
                pk_fma(X2v, mk2(gb.x, gb.y), hb)));
        t.x = fmaxf(t.x, 0.f);           // no v_pk_max_f32 on gfx950
        t.y = fmaxf(t.y, 0.f);
        acc2 = pk_fma(t, mk2(gb.z, gb.w), acc2);
    }
    const float logit = bias2[n] + acc2.x + acc2.y;
    const float u = 1.f / (1.f + __expf(-logit));

    // message: msg = sum_q c_q * exp2(s . xn_q - 2L|a|^2)
    const float4* __restrict__ pA = xnA[k];
    const float4* __restrict__ pB = xnB[k];
    v2f m0 = mk2(0.f, 0.f), m1 = mk2(0.f, 0.f);
    #pragma unroll 2
    for (int t2 = 0; t2 < Q_ / 2; t2 += 2) {
        const float4 A0 = pA[t2], A1 = pA[t2 + 1];
        const float4 B0 = pB[t2], B1 = pB[t2 + 1];
        v2f d0 = pk_fma(mk2(A0.x, A0.y), S0,
                 pk_fma(mk2(A0.z, A0.w), S1,
                 pk_fma(mk2(B0.x, B0.y), S2, RA)));
        v2f d1 = pk_fma(mk2(A1.x, A1.y), S0,
                 pk_fma(mk2(A1.z, A1.w), S1,
                 pk_fma(mk2(B1.x, B1.y), S2, RA)));
        v2f e0 = mk2(__builtin_amdgcn_exp2f(d0.x), __builtin_amdgcn_exp2f(d0.y));
        v2f e1 = mk2(__builtin_amdgcn_exp2f(d1.x), __builtin_amdgcn_exp2f(d1.y));
        m0 = pk_fma(mk2(B0.z, B0.w), e0, m0);
        m1 = pk_fma(mk2(B1.z, B1.w), e1, m1);
    }
    const float msg = (m0.x + m0.y) + (m1.x + m1.y);
    const float wval = u * msg;

    // ---- normalize over (k,p): block reduction of wval ----
    {
        float v = wval;
        #pragma unroll
        for (int off = 32; off > 0; off >>= 1) v += __shfl_down(v, off, 64);
        if (lane == 0) red[wave] = v;
        __syncthreads();
        if (tid == 0) {
            float s = 0.f;
            #pragma unroll
            for (int wv = 0; wv < 10; ++wv) s += red[wv];
            totalS = 1.f / (s + EPS_);
        }
        __syncthreads();
    }

    out[((size_t)b * N_ + n) * Q_ + tid] = wval * totalS;
}

extern "C" void kernel_launch(void* const* d_in, const int* in_sizes, int n_in,
                              void* d_out, int out_size, void* d_ws, size_t ws_size,
                              hipStream_t stream) {
    const float* X     = (const float*)d_in[0];
    const float* W     = (const float*)d_in[1];
    const float* feats = (const float*)d_in[2];
    const float* mu    = (const float*)d_in[3];
    const float* W1    = (const float*)d_in[4];
    const float* Wx    = (const float*)d_in[5];
    const float* b1    = (const float*)d_in[6];
    const float* W2    = (const float*)d_in[7];
    const float* bias2 = (const float*)d_in[8];
    const int*   nbr   = (const int*)d_in[9];
    float*       out   = (float*)d_out;

    dnbp_kernel<<<B_ * N_, Q_, 0, stream>>>(X, W, feats, mu, W1, Wx, b1, W2,
                                            bias2, nbr, out);
}

// Round 5
// 93.733 us; speedup vs baseline: 1.0336x; 1.0295x over previous
//
#include <hip/hip_runtime.h>
#include <hip/hip_bf16.h>

// Problem constants (B, N, K, P, D, F, H) = (8, 20, 2, 320, 3, 64, 64)
constexpr int B_ = 8, N_ = 20, K_ = 2, P_ = 320, D_ = 3, F_ = 64, H_ = 64;
constexpr int Q_ = K_ * P_;          // 640 rows = flattened (K,P)
constexpr float EPS_ = 1e-8f;
constexpr float LOG2E_ = 1.4426950408889634f;

typedef float v2f __attribute__((ext_vector_type(2)));

__device__ __forceinline__ v2f mk2(float a, float b) { v2f r; r.x = a; r.y = b; return r; }

__device__ __forceinline__ v2f pk_fma(v2f a, v2f b, v2f c) {
    v2f d;
    asm("v_pk_fma_f32 %0, %1, %2, %3" : "=v"(d) : "v"(a), "v"(b), "v"(c));
    return d;
}

// Minimal delta vs the PASSING R2 kernel: staging/layout/gate/normalize are
// verbatim R2. Only the q-pass changes: QUAD-SPLIT — thread tid serves its own
// quad of rows (tid&~3)+j over a quarter of the pairs, strided pi = 4i+(tid&3).
// Main VALU & exp counts per thread unchanged; LDS b128 reads drop 640 -> 160
// (the R2 result showed halving VALU was neutral => LDS return-BW bound).
// The mod-4 pair stride puts the 4 quarter-streams on disjoint bank-quads
// (bank = (16i + 4qt) % 32) -> conflict-free.
__global__ __launch_bounds__(Q_) void dnbp_kernel(
    const float* __restrict__ X,      // (B,N,K,P,D)
    const float* __restrict__ W,      // (B,N,K,P)
    const float* __restrict__ feats,  // (B,N,F)
    const float* __restrict__ mu,     // (N,K,D)
    const float* __restrict__ W1,     // (N,F,H)
    const float* __restrict__ Wx,     // (N,D,H)
    const float* __restrict__ b1,     // (N,H)
    const float* __restrict__ W2,     // (N,H)
    const float* __restrict__ bias2,  // (N,)
    const int* __restrict__ nbr,      // (N,2)
    float* __restrict__ out)          // (B,N,K,P) float32
{
    __shared__ float4 xnA[K_][P_];       // pair qi: (x_e,x_o,y_e,y_o), linear
    __shared__ float4 xnB[K_][P_];       // pair qi: (z_e,z_o,c_e,c_o)
    __shared__ float4 aTab[Q_];          // per-row (s0,s1,s2, -2L*ra2), s = 4L*a
    __shared__ float  part[Q_][4];       // per-row quarter partials
    __shared__ float4 gA[H_ / 2];        // (wx0_e,wx0_o,wx1_e,wx1_o)
    __shared__ float4 gB[H_ / 2];        // (wx2_e,wx2_o,w2_e,w2_o)
    __shared__ v2f    hb2[H_ / 2];       // (hf+b1) pairs
    __shared__ float  red[2 * 10];
    __shared__ float  sumW[2];
    __shared__ float  totalS;

    const int bn  = blockIdx.x;     // 0..159
    const int b   = bn / N_;
    const int n   = bn - b * N_;
    const int tid = threadIdx.x;    // 0..639
    const int wave = tid >> 6;
    const int lane = tid & 63;

    const int j0 = nbr[n * 2 + 0];
    const int j1 = nbr[n * 2 + 1];

    // ---- gate parameters: hf = feats[b,n] @ W1[n]; pair-SoA pack (threads 0..63) ----
    if (tid < H_) {
        const int h = tid;
        const float* fp  = feats + ((size_t)b * N_ + n) * F_;
        const float* w1p = W1 + (size_t)n * F_ * H_ + h;
        float acc = 0.f;
        #pragma unroll 8
        for (int f = 0; f < F_; ++f)
            acc = fmaf(fp[f], w1p[(size_t)f * H_], acc);
        const int hi = h >> 1, ho = h & 1;
        ((float*)&hb2[hi])[ho] = acc + b1[n * H_ + h];
        const float* wxp = Wx + (size_t)n * D_ * H_ + h;
        float* ga = (float*)&gA[hi];
        float* gb = (float*)&gB[hi];
        ga[ho]     = wxp[0];
        ga[2 + ho] = wxp[H_];
        gb[ho]     = wxp[2 * H_];
        gb[2 + ho] = W2[n * H_ + h];
    }

    // ---- stage both neighbors' points into pair-SoA (verbatim R2, linear qi) ----
    const int q  = tid;
    const int qi = q >> 1, qo = q & 1;
    float w0, w1, ew0, ew1;
    {
        const size_t base0 = ((size_t)b * N_ + j0) * Q_ + q;
        const float* xp = X + base0 * D_;
        const float x0 = xp[0], x1 = xp[1], x2 = xp[2];
        const float sq = x0 * x0 + x1 * x1 + x2 * x2;
        w0  = W[base0];
        ew0 = __builtin_amdgcn_exp2f(-2.f * LOG2E_ * sq);
        float* a  = (float*)&xnA[0][qi];
        float* bq = (float*)&xnB[0][qi];
        a[qo] = x0; a[2 + qo] = x1; bq[qo] = x2;
    }
    {
        const size_t base1 = ((size_t)b * N_ + j1) * Q_ + q;
        const float* xp = X + base1 * D_;
        const float x0 = xp[0], x1 = xp[1], x2 = xp[2];
        const float sq = x0 * x0 + x1 * x1 + x2 * x2;
        w1  = W[base1];
        ew1 = __builtin_amdgcn_exp2f(-2.f * LOG2E_ * sq);
        float* a  = (float*)&xnA[1][qi];
        float* bq = (float*)&xnB[1][qi];
        a[qo] = x0; a[2 + qo] = x1; bq[qo] = x2;
    }

    // ---- own-row params -> aTab; keep own x in regs for the gate ----
    const int kk = (tid >= P_) ? 1 : 0;
    const int pp = tid - kk * P_;
    float x0o, x1o, x2o;
    {
        const size_t rowbase = (((size_t)b * N_ + n) * K_ + kk) * P_ + pp;
        const float* xp = X + rowbase * D_;
        x0o = xp[0]; x1o = xp[1]; x2o = xp[2];
        const float* mup = mu + (n * K_ + kk) * D_;
        const float a0 = x0o - mup[0];
        const float a1 = x1o - mup[1];
        const float a2 = x2o - mup[2];
        const float ra2 = a0 * a0 + a1 * a1 + a2 * a2;
        aTab[tid] = make_float4(a0 * (4.f * LOG2E_), a1 * (4.f * LOG2E_),
                                a2 * (4.f * LOG2E_), -2.f * LOG2E_ * ra2);
    }

    // ---- block-reduce neighbor weight sums ----
    {
        float v0 = w0, v1 = w1;
        #pragma unroll
        for (int off = 32; off > 0; off >>= 1) {
            v0 += __shfl_down(v0, off, 64);
            v1 += __shfl_down(v1, off, 64);
        }
        if (lane == 0) { red[wave * 2] = v0; red[wave * 2 + 1] = v1; }
        __syncthreads();
        if (tid == 0) {
            float s0 = 0.f, s1 = 0.f;
            #pragma unroll
            for (int wv = 0; wv < 10; ++wv) { s0 += red[wv * 2]; s1 += red[wv * 2 + 1]; }
            sumW[0] = 1.f / (s0 + EPS_);
            sumW[1] = 1.f / (s1 + EPS_);
        }
        __syncthreads();
    }

    // ---- fold normalized weight into c slots (verbatim R2) ----
    ((float*)&xnB[0][qi])[2 + qo] = w0 * ew0 * sumW[0];
    ((float*)&xnB[1][qi])[2 + qo] = w1 * ew1 * sumW[1];
    __syncthreads();

    // ---- quad-split q-pass: 4 rows (own quad) x 80 strided pairs ----
    const int base = tid & ~3;           // quad base row (same k: 320 % 4 == 0)
    const int qt   = tid & 3;            // pair-stride phase
    const float4* __restrict__ tabA = xnA[kk];
    const float4* __restrict__ tabB = xnB[kk];

    v2f S0[4], S1[4], S2[4], RA[4];
    #pragma unroll
    for (int j = 0; j < 4; ++j) {
        const float4 av = aTab[base + j];
        S0[j] = mk2(av.x, av.x);
        S1[j] = mk2(av.y, av.y);
        S2[j] = mk2(av.z, av.z);
        RA[j] = mk2(av.w, av.w);
    }
    v2f acc[4];
    #pragma unroll
    for (int j = 0; j < 4; ++j) acc[j] = mk2(0.f, 0.f);

    #pragma unroll 2
    for (int i = 0; i < P_ / 4; ++i) {   // 80 pairs per thread
        const int pi = 4 * i + qt;
        const float4 A  = tabA[pi];
        const float4 Bv = tabB[pi];
        #pragma unroll
        for (int j = 0; j < 4; ++j) {
            const v2f d = pk_fma(mk2(A.x, A.y), S0[j],
                          pk_fma(mk2(A.z, A.w), S1[j],
                          pk_fma(mk2(Bv.x, Bv.y), S2[j], RA[j])));
            const v2f e = mk2(__builtin_amdgcn_exp2f(d.x),
                              __builtin_amdgcn_exp2f(d.y));
            acc[j] = pk_fma(mk2(Bv.z, Bv.w), e, acc[j]);
        }
    }
    #pragma unroll
    for (int j = 0; j < 4; ++j)
        part[base + j][qt] = acc[j].x + acc[j].y;

    __syncthreads();

    // ---- final: combine quarter partials, gate, normalize ----
    const float* pr = part[tid];
    const float msg = (pr[0] + pr[1]) + (pr[2] + pr[3]);

    // gate: u = sigmoid( sum_h relu(hf+b1 + X.Wx)[h] * W2[h] + bias2 )
    const v2f X0v = mk2(x0o, x0o), X1v = mk2(x1o, x1o), X2v = mk2(x2o, x2o);
    v2f acc2 = mk2(0.f, 0.f);
    #pragma unroll 4
    for (int i = 0; i < H_ / 2; ++i) {
        const float4 ga = gA[i];
        const float4 gb = gB[i];
        const v2f   hb = hb2[i];
        v2f t = pk_fma(X0v, mk2(ga.x, ga.y),
                pk_fma(X1v, mk2(ga.z, ga.w),
                pk_fma(X2v, mk2(gb.x, gb.y), hb)));
        t.x = fmaxf(t.x, 0.f);           // no v_pk_max_f32 on gfx950
        t.y = fmaxf(t.y, 0.f);
        acc2 = pk_fma(t, mk2(gb.z, gb.w), acc2);
    }
    const float logit = bias2[n] + acc2.x + acc2.y;
    const float u = 1.f / (1.f + __expf(-logit));
    const float wval = u * msg;

    // ---- normalize over (k,p): block reduction of wval ----
    {
        float v = wval;
        #pragma unroll
        for (int off = 32; off > 0; off >>= 1) v += __shfl_down(v, off, 64);
        if (lane == 0) red[wave] = v;
        __syncthreads();
        if (tid == 0) {
            float s = 0.f;
            #pragma unroll
            for (int wv = 0; wv < 10; ++wv) s += red[wv];
            totalS = 1.f / (s + EPS_);
        }
        __syncthreads();
    }

    out[((size_t)b * N_ + n) * Q_ + tid] = wval * totalS;
}

extern "C" void kernel_launch(void* const* d_in, const int* in_sizes, int n_in,
                              void* d_out, int out_size, void* d_ws, size_t ws_size,
                              hipStream_t stream) {
    const float* X     = (const float*)d_in[0];
    const float* W     = (const float*)d_in[1];
    const float* feats = (const float*)d_in[2];
    const float* mu    = (const float*)d_in[3];
    const float* W1    = (const float*)d_in[4];
    const float* Wx    = (const float*)d_in[5];
    const float* b1    = (const float*)d_in[6];
    const float* W2    = (const float*)d_in[7];
    const float* bias2 = (const float*)d_in[8];
    const int*   nbr   = (const int*)d_in[9];
    float*       out   = (float*)d_out;

    dnbp_kernel<<<B_ * N_, Q_, 0, stream>>>(X, W, feats, mu, W1, Wx, b1, W2,
                                            bias2, nbr, out);
}

// Round 10
// 91.576 us; speedup vs baseline: 1.0579x; 1.0235x over previous
//
#include <hip/hip_runtime.h>

// Problem constants (B, N, K, P, D, F, H) = (8, 20, 2, 320, 3, 64, 64)
constexpr int B_ = 8, N_ = 20, K_ = 2, P_ = 320, D_ = 3, F_ = 64, H_ = 64;
constexpr int Q_ = K_ * P_;          // 640 rows = flattened (K,P)
constexpr float EPS_ = 1e-8f;
constexpr float LOG2E_ = 1.4426950408889634f;
constexpr int TILES_ = 10;           // 64-row tiles per (b,n)
constexpr int ROWS_  = 64;           // rows per tile; tile>=5 -> k=1 (uniform)

// ZERO inline asm. Every prior accuracy failure (R3/R4/R6/R7/R8) contained
// v_pk_fma_f32 inline asm under deep unroll/high pressure; the two passes had
// the fewest asm instances, and R0->R2 measured packed math as NEUTRAL anyway.
// This round: the 1600-block occupancy structure (all 256 CUs, ~24 waves/CU
// so VALU and transcendental pipes overlap across waves) in plain scalar HIP.
// (Resubmission of R9 — container infra failure, kernel never ran.)
__global__ __launch_bounds__(256) void main_kernel(
    const float* __restrict__ X,      // (B,N,K,P,D)
    const float* __restrict__ W,      // (B,N,K,P)
    const float* __restrict__ feats,  // (B,N,F)
    const float* __restrict__ mu,     // (N,K,D)
    const float* __restrict__ W1,     // (N,F,H)
    const float* __restrict__ Wx,     // (N,D,H)
    const float* __restrict__ b1,     // (N,H)
    const float* __restrict__ W2,     // (N,H)
    const float* __restrict__ bias2,  // (N,)
    const int* __restrict__ nbr,      // (N,2)
    float* __restrict__ wsPart,       // (1600,) tile sums
    float* __restrict__ out)          // (B,N,K,P) unnormalized
{
    __shared__ float4 sQ[Q_];            // neighbor point q: (x, y, z, c)
    __shared__ float4 aT[ROWS_];         // row: (4L*a0, 4L*a1, 4L*a2, -2L*|a|^2)
    __shared__ float4 xT[ROWS_];         // row: (x0, x1, x2, 0)
    __shared__ float4 gT[H_];            // h: (wx0, wx1, wx2, w2)
    __shared__ float  hbT[H_];           // h: hf + b1
    __shared__ float  part[ROWS_][17];   // row x slice partials (16 used)
    __shared__ float  red[4];
    __shared__ float  invW;              // 1/(sum W_neighbor + EPS)

    const int blk  = blockIdx.x;         // 0..1599
    const int bn   = blk / TILES_;
    const int tile = blk - bn * TILES_;
    const int b    = bn / N_;
    const int n    = bn - b * N_;
    const int tid  = threadIdx.x;        // 0..255
    const int wave = tid >> 6;
    const int lane = tid & 63;
    const int k    = (tile >= 5) ? 1 : 0;
    const int r0   = tile * ROWS_;       // row base in (k*320+p) flattening
    const int j    = nbr[n * 2 + k];     // component k pairs with neighbor k

    // ---- stage neighbor j's 640 points: sQ[q] = (x, y, z, w*exp2(-2L|x|^2)) ----
    const size_t nbase = ((size_t)b * N_ + j) * Q_;
    float wsum = 0.f;
    for (int i = tid; i < Q_; i += 256) {
        const float* xp = X + (nbase + i) * D_;
        const float x0 = xp[0], x1 = xp[1], x2 = xp[2];
        const float sq = x0 * x0 + x1 * x1 + x2 * x2;
        const float w  = W[nbase + i];
        const float c  = w * __builtin_amdgcn_exp2f(-2.f * LOG2E_ * sq);
        sQ[i] = make_float4(x0, x1, x2, c);
        wsum += w;
    }
    {   // block-reduce neighbor weight sum
        float v = wsum;
        #pragma unroll
        for (int off = 32; off > 0; off >>= 1) v += __shfl_down(v, off, 64);
        if (lane == 0) red[wave] = v;
    }

    // ---- per-row params + gate tables (threads 0..63) ----
    if (tid < ROWS_) {
        const int gr = r0 + tid;         // flattened row of this (b,n)
        const float* xp = X + ((size_t)bn * Q_ + gr) * D_;
        const float x0 = xp[0], x1 = xp[1], x2 = xp[2];
        const float* mup = mu + (n * K_ + k) * D_;
        const float a0 = x0 - mup[0];
        const float a1 = x1 - mup[1];
        const float a2 = x2 - mup[2];
        const float ra2 = a0 * a0 + a1 * a1 + a2 * a2;
        aT[tid] = make_float4(a0 * (4.f * LOG2E_), a1 * (4.f * LOG2E_),
                              a2 * (4.f * LOG2E_), -2.f * LOG2E_ * ra2);
        xT[tid] = make_float4(x0, x1, x2, 0.f);

        // hb gemv: hf = feats[b,n] @ W1[n][:,h] + b1[n,h]
        const int h = tid;
        const float* fp  = feats + (size_t)bn * F_;
        const float* w1p = W1 + (size_t)n * F_ * H_ + h;
        float acc = 0.f;
        #pragma unroll 8
        for (int f = 0; f < F_; ++f)
            acc = fmaf(fp[f], w1p[(size_t)f * H_], acc);
        hbT[h] = acc + b1[n * H_ + h];
        const float* wxp = Wx + (size_t)n * D_ * H_ + h;
        gT[h] = make_float4(wxp[0], wxp[H_], wxp[2 * H_], W2[n * H_ + h]);
    }
    __syncthreads();

    if (tid == 0)
        invW = 1.f / (((red[0] + red[1]) + (red[2] + red[3])) + EPS_);

    // ---- q-pass: thread = (row-group g: 4 rows, slice s: 40 strided q) ----
    const int g = tid >> 4;              // 0..15 (rows 4g..4g+3 of the tile)
    const int s = tid & 15;              // 0..15
    float S0[4], S1[4], S2[4], RA[4], acc[4];
    #pragma unroll
    for (int jj = 0; jj < 4; ++jj) {
        const float4 av = aT[g * 4 + jj];
        S0[jj] = av.x; S1[jj] = av.y; S2[jj] = av.z; RA[jj] = av.w;
        acc[jj] = 0.f;
    }
    #pragma unroll 4
    for (int i = 0; i < Q_ / 16; ++i) {  // 40 q per thread
        const float4 Pq = sQ[i * 16 + s];
        #pragma unroll
        for (int jj = 0; jj < 4; ++jj) {
            const float d = fmaf(Pq.x, S0[jj],
                            fmaf(Pq.y, S1[jj],
                            fmaf(Pq.z, S2[jj], RA[jj])));
            acc[jj] = fmaf(Pq.w, __builtin_amdgcn_exp2f(d), acc[jj]);
        }
    }
    #pragma unroll
    for (int jj = 0; jj < 4; ++jj)
        part[g * 4 + jj][s] = acc[jj];

    __syncthreads();

    // ---- tail (wave 0): combine slices, gate, scale, out + tile partial ----
    if (tid < ROWS_) {
        const int row = tid;
        const float* pr = part[row];
        const float msg =
            (((pr[0] + pr[1]) + (pr[2] + pr[3])) + ((pr[4] + pr[5]) + (pr[6] + pr[7]))) +
            (((pr[8] + pr[9]) + (pr[10] + pr[11])) + ((pr[12] + pr[13]) + (pr[14] + pr[15])));

        const float4 xr = xT[row];
        float accg = bias2[n];
        #pragma unroll 8
        for (int h = 0; h < H_; ++h) {
            const float4 gv = gT[h];
            float t = fmaf(xr.x, gv.x, fmaf(xr.y, gv.y, fmaf(xr.z, gv.z, hbT[h])));
            t = fmaxf(t, 0.f);
            accg = fmaf(t, gv.w, accg);
        }
        const float u = 1.f / (1.f + __expf(-accg));
        const float wval = u * msg * invW;   // invW: exact linear factor

        out[(size_t)bn * Q_ + r0 + row] = wval;

        float v = wval;
        #pragma unroll
        for (int off = 32; off > 0; off >>= 1) v += __shfl_down(v, off, 64);
        if (tid == 0) wsPart[blk] = v;
    }
}

// ---------------- K2: normalize over (k,p) per (b,n) ----------------
__global__ __launch_bounds__(Q_) void norm_kernel(
    const float* __restrict__ wsPart, float* __restrict__ out)
{
    const int bn = blockIdx.x;
    const float* p = wsPart + bn * TILES_;
    float s0 = 0.f, s1 = 0.f;
    #pragma unroll
    for (int t = 0; t < TILES_ / 2; ++t) { s0 += p[2 * t]; s1 += p[2 * t + 1]; }
    const float inv = 1.f / ((s0 + s1) + EPS_);
    out[(size_t)bn * Q_ + threadIdx.x] *= inv;
}

extern "C" void kernel_launch(void* const* d_in, const int* in_sizes, int n_in,
                              void* d_out, int out_size, void* d_ws, size_t ws_size,
                              hipStream_t stream) {
    const float* X     = (const float*)d_in[0];
    const float* W     = (const float*)d_in[1];
    const float* feats = (const float*)d_in[2];
    const float* mu    = (const float*)d_in[3];
    const float* W1    = (const float*)d_in[4];
    const float* Wx    = (const float*)d_in[5];
    const float* b1    = (const float*)d_in[6];
    const float* W2    = (const float*)d_in[7];
    const float* bias2 = (const float*)d_in[8];
    const int*   nbr   = (const int*)d_in[9];
    float*       out   = (float*)d_out;
    float*       wsPart = (float*)d_ws;   // 1600 floats

    main_kernel<<<B_ * N_ * TILES_, 256, 0, stream>>>(
        X, W, feats, mu, W1, Wx, b1, W2, bias2, nbr, wsPart, out);
    norm_kernel<<<B_ * N_, Q_, 0, stream>>>(wsPart, out);
}